// Round 10
// baseline (141.789 us; speedup 1.0000x reference)
//
#include <hip/hip_runtime.h>

#define VQ_EPS    1e-12f
#define VQ_WINDOW 0.01f     // >= ~10 sigma of the bf16 score error; proven R6/R8/R9 (absmax 0)
#define VQ_CAP    12

typedef short bf16x8 __attribute__((ext_vector_type(8)));   // 8 bf16 bit-patterns = 4 VGPRs
typedef float f32x4  __attribute__((ext_vector_type(4)));

static __device__ __forceinline__ unsigned short f2bf(float f) {
    unsigned u = __float_as_uint(f);
    u += 0x7fffu + ((u >> 16) & 1u);     // RNE
    return (unsigned short)(u >> 16);
}

// Order-preserving float->uint map (handles negative exact scores).
static __device__ __forceinline__ unsigned f2ord(float f) {
    unsigned b = __float_as_uint(f);
    return (b & 0x80000000u) ? ~b : (b | 0x80000000u);
}

// Prep kernel: normalize codebook rows (fp32, mirrors F.normalize), emit:
//   cbn  [512][64] fp32      -- exact rescore + codes-gather epilogue
//   cbB  [32 ntile][2 kstep][64 lane][8] bf16 -- B-fragment-linear for
//        mfma_f32_16x16x32_bf16 (layout proven correct R5-R9)
//   kn2  [512] fp32          -- sum(cbn^2) AFTER normalization (reference rounding)
//   kn2p [512] fp32          -- kn2 + 2.0f (keeps approx scores > 0 for uint packing)
__global__ __launch_bounds__(64) void cb_prep_kernel(const float* __restrict__ cb,
                                                     float* __restrict__ cbn,
                                                     unsigned short* __restrict__ cbB,
                                                     float* __restrict__ kn2,
                                                     float* __restrict__ kn2p) {
    const int k = blockIdx.x;       // 512 codes
    const int c = threadIdx.x;      // 64 channels
    float v = cb[k * 64 + c];
    float s = v * v;
    #pragma unroll
    for (int off = 32; off > 0; off >>= 1) s += __shfl_xor(s, off, 64);
    float n = sqrtf(s);
    float cn = v / fmaxf(n, VQ_EPS);
    cbn[k * 64 + c] = cn;

    const int ntile = k >> 4, col = k & 15;
    const int ks = c >> 5, quad = (c >> 3) & 3, j = c & 7;
    cbB[(((ntile * 2 + ks) * 64) + quad * 16 + col) * 8 + j] = f2bf(cn);

    float s2 = cn * cn;
    #pragma unroll
    for (int off = 32; off > 0; off >>= 1) s2 += __shfl_xor(s2, off, 64);
    if (c == 0) { kn2[k] = s2; kn2p[k] = s2 + 2.0f; }
}

// Main kernel: 1024 blocks x 256 thr (4 waves). Each wave scores 32 pixels
// (TWO 16-row A-fragment sets) against the same streamed B fragments ->
// B traffic per pixel halves vs R9. Block covers 2 rows (wave w: row w>>1,
// pixels (w&1)*32 .. +31). B streams from global (cbB 64 KB, L2-resident,
// 1 KB contiguous per wave-load). Safety recipe (R8/R9, proven): shfls only
// in uniform code; LDS init & candidate writes wave-owned; cross-wave LDS
// reads only after __syncthreads; rescore is per-lane (2 lanes/pixel).
__global__ __launch_bounds__(256) void vq_mfma_kernel(const float* __restrict__ x,
                                                      const float* __restrict__ cbn,
                                                      const unsigned short* __restrict__ cbB,
                                                      const float* __restrict__ kn2,
                                                      const float* __restrict__ kn2p,
                                                      float* __restrict__ codes,
                                                      float* __restrict__ idxout) {
    __shared__ int    scnt[128];
    __shared__ int    slist[128][VQ_CAP];
    __shared__ unsigned long long spack[128];
    __shared__ float  sm2[128];

    const int t    = threadIdx.x;
    const int lane = t & 63;
    const int wid  = t >> 6;
    const int col  = lane & 15;
    const int quad = lane >> 4;

    const int row_local = wid >> 1;            // 0..1 (row within block)
    const int woff      = (wid & 1) * 32;      // pixel offset within row
    const int rowid     = blockIdx.x * 2 + row_local;   // 0..2047 = (b,h)
    const int b = rowid >> 6;
    const int h = rowid & 63;
    const float* xblk = x + ((size_t)b << 18) + (h << 6);   // + c*4096 + w
    const int pixbase = row_local * 64 + woff;  // block-pixel base of this wave

    // ---- wave-owned LDS init (no cross-wave hazard before B1) ----
    if (quad == 0) {
        scnt[pixbase + col]       = 0;
        scnt[pixbase + 16 + col]  = 0;
        spack[pixbase + col]      = 0xFFFFFFFFFFFFFFFFull;
        spack[pixbase + 16 + col] = 0xFFFFFFFFFFFFFFFFull;
    }

    // ---- A fragments: two 16-pixel sets, channels quad*8+j (+32 per ks) ----
    float xvA[16], xvB[16];
    #pragma unroll
    for (int ks = 0; ks < 2; ++ks)
        #pragma unroll
        for (int j = 0; j < 8; ++j) {
            const size_t coff = (size_t)(ks * 32 + quad * 8 + j) * 4096;
            xvA[ks * 8 + j] = xblk[coff + woff + col];
            xvB[ks * 8 + j] = xblk[coff + woff + 16 + col];
        }

    float sspA = 0.0f, sspB = 0.0f;
    #pragma unroll
    for (int i = 0; i < 16; ++i) {
        sspA = fmaf(xvA[i], xvA[i], sspA);
        sspB = fmaf(xvB[i], xvB[i], sspB);
    }
    sspA += __shfl_xor(sspA, 16);    // uniform code: all 64 lanes execute
    sspA += __shfl_xor(sspA, 32);
    sspB += __shfl_xor(sspB, 16);
    sspB += __shfl_xor(sspB, 32);
    const float m2aA = -2.0f * (1.0f / fmaxf(sqrtf(sspA), VQ_EPS));
    const float m2aB = -2.0f * (1.0f / fmaxf(sqrtf(sspB), VQ_EPS));

    float m2r[2][4];
    #pragma unroll
    for (int r = 0; r < 4; ++r) {
        m2r[0][r] = __shfl(m2aA, quad * 4 + r);    // uniform shfl
        m2r[1][r] = __shfl(m2aB, quad * 4 + r);
    }
    if (quad == 0) {                   // hand m2 to the rescore phase via LDS
        sm2[pixbase + col]      = m2aA;
        sm2[pixbase + 16 + col] = m2aB;
    }

    bf16x8 afragA[2], afragB[2];
    #pragma unroll
    for (int ks = 0; ks < 2; ++ks)
        #pragma unroll
        for (int j = 0; j < 8; ++j) {
            ((unsigned short*)&afragA[ks])[j] = f2bf(xvA[ks * 8 + j]);
            ((unsigned short*)&afragB[ks])[j] = f2bf(xvB[ks * 8 + j]);
        }

    const bf16x8* gBf = (const bf16x8*)cbB;

    // ---- pass 1: MFMA scan, packed running approx argmin (both sets) ----
    unsigned run[2][4] = {{0xFFFFFFFFu, 0xFFFFFFFFu, 0xFFFFFFFFu, 0xFFFFFFFFu},
                          {0xFFFFFFFFu, 0xFFFFFFFFu, 0xFFFFFFFFu, 0xFFFFFFFFu}};
    #pragma unroll 4
    for (int nt = 0; nt < 32; ++nt) {
        bf16x8 b0 = gBf[(nt * 2 + 0) * 64 + lane];     // 1 KB coalesced, L2-hot
        bf16x8 b1 = gBf[(nt * 2 + 1) * 64 + lane];
        f32x4 cA = {0.0f, 0.0f, 0.0f, 0.0f};
        cA = __builtin_amdgcn_mfma_f32_16x16x32_bf16(afragA[0], b0, cA, 0, 0, 0);
        cA = __builtin_amdgcn_mfma_f32_16x16x32_bf16(afragA[1], b1, cA, 0, 0, 0);
        f32x4 cB = {0.0f, 0.0f, 0.0f, 0.0f};
        cB = __builtin_amdgcn_mfma_f32_16x16x32_bf16(afragB[0], b0, cB, 0, 0, 0);
        cB = __builtin_amdgcn_mfma_f32_16x16x32_bf16(afragB[1], b1, cB, 0, 0, 0);
        const float    kn   = kn2p[nt * 16 + col];     // L1-hot
        const unsigned kidx = (unsigned)(nt * 16 + col);
        #pragma unroll
        for (int r = 0; r < 4; ++r) {
            float sA = fmaf(m2r[0][r], cA[r], kn);     // (~0.6, 5.2) -> uint-orderable
            float sB = fmaf(m2r[1][r], cB[r], kn);
            run[0][r] = min(run[0][r], (__float_as_uint(sA) & 0xFFFFFE00u) | kidx);
            run[1][r] = min(run[1][r], (__float_as_uint(sB) & 0xFFFFFE00u) | kidx);
        }
    }

    // ---- thresholds: cross-lane min within each 16-lane col group (uniform) ----
    float thr[2][4];
    #pragma unroll
    for (int s = 0; s < 2; ++s)
        #pragma unroll
        for (int r = 0; r < 4; ++r) {
            unsigned v = run[s][r];
            v = min(v, (unsigned)__shfl_xor((int)v, 1));
            v = min(v, (unsigned)__shfl_xor((int)v, 2));
            v = min(v, (unsigned)__shfl_xor((int)v, 4));
            v = min(v, (unsigned)__shfl_xor((int)v, 8));
            thr[s][r] = __uint_as_float(v & 0xFFFFFE00u) + VQ_WINDOW;
        }

    // ---- pass 2: bit-identical recompute, collect candidates (wave-owned) ----
    #pragma unroll 4
    for (int nt = 0; nt < 32; ++nt) {
        bf16x8 b0 = gBf[(nt * 2 + 0) * 64 + lane];
        bf16x8 b1 = gBf[(nt * 2 + 1) * 64 + lane];
        f32x4 cA = {0.0f, 0.0f, 0.0f, 0.0f};
        cA = __builtin_amdgcn_mfma_f32_16x16x32_bf16(afragA[0], b0, cA, 0, 0, 0);
        cA = __builtin_amdgcn_mfma_f32_16x16x32_bf16(afragA[1], b1, cA, 0, 0, 0);
        f32x4 cB = {0.0f, 0.0f, 0.0f, 0.0f};
        cB = __builtin_amdgcn_mfma_f32_16x16x32_bf16(afragB[0], b0, cB, 0, 0, 0);
        cB = __builtin_amdgcn_mfma_f32_16x16x32_bf16(afragB[1], b1, cB, 0, 0, 0);
        const float kn   = kn2p[nt * 16 + col];
        const int   kidx = nt * 16 + col;
        #pragma unroll
        for (int r = 0; r < 4; ++r) {
            float sA = fmaf(m2r[0][r], cA[r], kn);
            if (sA <= thr[0][r]) {
                int pix = pixbase + quad * 4 + r;          // wave-owned pixel
                int pos = atomicAdd(&scnt[pix], 1);
                if (pos < VQ_CAP) slist[pix][pos] = kidx;
            }
            float sB = fmaf(m2r[1][r], cB[r], kn);
            if (sB <= thr[1][r]) {
                int pix = pixbase + 16 + quad * 4 + r;
                int pos = atomicAdd(&scnt[pix], 1);
                if (pos < VQ_CAP) slist[pix][pos] = kidx;
            }
        }
    }
    __syncthreads();   // B1: candidates + sm2 block-visible

    // ---- exact fp32 rescore: 2 lanes/pixel, per-lane only (no shfl here) ----
    {
        const int P   = t >> 1;                    // block pixel 0..127
        const int sub = t & 1;
        const int cnt = scnt[P];
        if (cnt > 1) {
            const int rw  = P >> 6;
            const int rid = blockIdx.x * 2 + rw;
            const float* xp = x + ((size_t)(rid >> 6) << 18) + ((rid & 63) << 6) + (P & 63);
            const float m2P = sm2[P];
            if (cnt <= VQ_CAP) {
                for (int i = sub; i < cnt; i += 2) {
                    const int k = slist[P][i];
                    const float* cr = cbn + (size_t)k * 64;
                    float dot = 0.0f;
                    #pragma unroll 8
                    for (int c = 0; c < 64; ++c)
                        dot = fmaf(xp[(size_t)c * 4096], cr[c], dot);  // R1 order
                    float s = fmaf(m2P, dot, kn2[k]);
                    unsigned long long key =
                        ((unsigned long long)f2ord(s) << 32) | (unsigned)k;
                    atomicMin(&spack[P], key);
                }
            } else {   // statistically dead overflow: exact scan of all codes
                for (int k = sub; k < 512; k += 2) {
                    const float* cr = cbn + (size_t)k * 64;
                    float dot = 0.0f;
                    #pragma unroll 8
                    for (int c = 0; c < 64; ++c)
                        dot = fmaf(xp[(size_t)c * 4096], cr[c], dot);
                    float s = fmaf(m2P, dot, kn2[k]);
                    unsigned long long key =
                        ((unsigned long long)f2ord(s) << 32) | (unsigned)k;
                    atomicMin(&spack[P], key);
                }
            }
        }
    }
    __syncthreads();   // B2: rescore results block-visible

    // ---- winner + outputs: 2 threads/pixel, each writes 32 channels ----
    {
        const int P    = t >> 1;
        const int half = t & 1;
        const int cnt  = scnt[P];
        const int bk   = (cnt == 1) ? slist[P][0]
                                    : (int)(spack[P] & 0xFFFFFFFFull);
        const int rw  = P >> 6;
        const int rid = blockIdx.x * 2 + rw;
        const int pb  = rid >> 6;
        const int ph  = rid & 63;
        const int w   = P & 63;

        if (half == 0) idxout[rid * 64 + w] = (float)bk;

        const float4* crow = (const float4*)(cbn + (size_t)bk * 64) + half * 8;
        float* cp = codes + ((size_t)pb << 18) + (ph << 6) + w;
        #pragma unroll
        for (int q = 0; q < 8; ++q) {
            float4 v = crow[q];
            const int c0 = half * 32 + q * 4;
            cp[(size_t)(c0 + 0) * 4096] = v.x;
            cp[(size_t)(c0 + 1) * 4096] = v.y;
            cp[(size_t)(c0 + 2) * 4096] = v.z;
            cp[(size_t)(c0 + 3) * 4096] = v.w;
        }
    }
}

extern "C" void kernel_launch(void* const* d_in, const int* in_sizes, int n_in,
                              void* d_out, int out_size, void* d_ws, size_t ws_size,
                              hipStream_t stream) {
    const float* x  = (const float*)d_in[0];   // [32,64,64,64] fp32
    const float* cb = (const float*)d_in[1];   // [512,64] fp32

    float*          cbn  = (float*)d_ws;                       // 128 KB
    unsigned short* cbB  = (unsigned short*)(cbn + 512 * 64);  // 64 KB (frag-linear bf16)
    float*          kn2  = (float*)(cbB + 32768);              // 2 KB
    float*          kn2p = kn2 + 512;                          // 2 KB

    float* codes  = (float*)d_out;                             // 32*64*64*64 floats
    float* idxout = codes + (size_t)32 * 64 * 64 * 64;         // 131072 floats

    cb_prep_kernel<<<512, 64, 0, stream>>>(cb, cbn, cbB, kn2, kn2p);
    vq_mfma_kernel<<<1024, 256, 0, stream>>>(x, cbn, cbB, kn2, kn2p, codes, idxout);
}

// Round 11
// 130.311 us; speedup vs baseline: 1.0881x; 1.0881x over previous
//
#include <hip/hip_runtime.h>

#define VQ_EPS    1e-12f
#define VQ_WINDOW 0.01f     // >= ~14 sigma of the bf16 score error; proven R6-R10 (absmax 0)
#define VQ_CAP    12

typedef short bf16x8 __attribute__((ext_vector_type(8)));   // 8 bf16 bit-patterns = 4 VGPRs
typedef float f32x4  __attribute__((ext_vector_type(4)));

static __device__ __forceinline__ unsigned short f2bf(float f) {
    unsigned u = __float_as_uint(f);
    u += 0x7fffu + ((u >> 16) & 1u);     // RNE
    return (unsigned short)(u >> 16);
}

// Order-preserving float->uint map (handles negative exact scores).
static __device__ __forceinline__ unsigned f2ord(float f) {
    unsigned b = __float_as_uint(f);
    return (b & 0x80000000u) ? ~b : (b | 0x80000000u);
}

// Prep kernel: normalize codebook rows (fp32, mirrors F.normalize), emit:
//   cbn  [512][64] fp32      -- exact rescore + codes-gather epilogue
//   cbB  [32 ntile][2 kstep][64 lane][8] bf16 -- B-fragment-linear for
//        mfma_f32_16x16x32_bf16 (layout proven correct R5-R10)
//   kn2  [512] fp32          -- sum(cbn^2) AFTER normalization (reference rounding)
//   kn2p [512] fp32          -- kn2 + 2.0f (keeps approx scores > 0 for uint packing)
__global__ __launch_bounds__(64) void cb_prep_kernel(const float* __restrict__ cb,
                                                     float* __restrict__ cbn,
                                                     unsigned short* __restrict__ cbB,
                                                     float* __restrict__ kn2,
                                                     float* __restrict__ kn2p) {
    const int k = blockIdx.x;       // 512 codes
    const int c = threadIdx.x;      // 64 channels
    float v = cb[k * 64 + c];
    float s = v * v;
    #pragma unroll
    for (int off = 32; off > 0; off >>= 1) s += __shfl_xor(s, off, 64);
    float n = sqrtf(s);
    float cn = v / fmaxf(n, VQ_EPS);
    cbn[k * 64 + c] = cn;

    const int ntile = k >> 4, col = k & 15;
    const int ks = c >> 5, quad = (c >> 3) & 3, j = c & 7;
    cbB[(((ntile * 2 + ks) * 64) + quad * 16 + col) * 8 + j] = f2bf(cn);

    float s2 = cn * cn;
    #pragma unroll
    for (int off = 32; off > 0; off >>= 1) s2 += __shfl_xor(s2, off, 64);
    if (c == 0) { kn2[k] = s2; kn2p[k] = s2 + 2.0f; }
}

// Main kernel: 2048 blocks x 256 thr (R9 chassis: 1 row/block, 16 px/wave).
// Pass 1 tracks TOP-2 packed keys per (lane,r) slot. Any within-window code
// is either a slot-min1 (collected straight from registers, no extra memory)
// or forces its slot's min2 <= thr -> the wave raises a uniform flag
// (__ballot) and runs the full R9 pass-2 recompute as fallback (~25-30% of
// waves). Unflagged waves skip 64 B-loads + 64 MFMAs + the scoring VALU.
// Safety recipe (R8/R9, proven): shfls/ballot only in uniform code; LDS
// init + candidate pushes wave-owned; cross-wave reads after barriers;
// rescore per-lane only.
__global__ __launch_bounds__(256) void vq_mfma_kernel(const float* __restrict__ x,
                                                      const float* __restrict__ cbn,
                                                      const unsigned short* __restrict__ cbB,
                                                      const float* __restrict__ kn2,
                                                      const float* __restrict__ kn2p,
                                                      float* __restrict__ codes,
                                                      float* __restrict__ idxout) {
    __shared__ int    scnt[64];
    __shared__ int    slist[64][VQ_CAP];
    __shared__ unsigned long long spack[64];

    const int t    = threadIdx.x;
    const int lane = t & 63;
    const int wid  = t >> 6;
    const int col  = lane & 15;
    const int quad = lane >> 4;
    const int wpix = wid * 16 + col;      // col-group's pixel (w coordinate)

    const int rowid = blockIdx.x;         // 0..2047 = (b,h)
    const int b = rowid >> 6;
    const int h = rowid & 63;
    const float* xblk = x + ((size_t)b << 18) + (h << 6);   // + c*4096 + w

    if (quad == 0) { scnt[wpix] = 0; spack[wpix] = 0xFFFFFFFFFFFFFFFFull; }

    // ---- A fragments: 16 channels of this lane's pixel, from global ----
    float xv[16];
    #pragma unroll
    for (int ks = 0; ks < 2; ++ks)
        #pragma unroll
        for (int j = 0; j < 8; ++j)
            xv[ks * 8 + j] = xblk[(size_t)(ks * 32 + quad * 8 + j) * 4096 + wpix];

    float ssp = 0.0f;
    #pragma unroll
    for (int i = 0; i < 16; ++i) ssp = fmaf(xv[i], xv[i], ssp);
    ssp += __shfl_xor(ssp, 16);      // uniform code: all 64 lanes execute
    ssp += __shfl_xor(ssp, 32);
    const float m2a = -2.0f * (1.0f / fmaxf(sqrtf(ssp), VQ_EPS));
    float m2r[4];
    #pragma unroll
    for (int r = 0; r < 4; ++r) m2r[r] = __shfl(m2a, quad * 4 + r);  // uniform
    const float m2P = __shfl(m2a, lane >> 2);   // uniform: m2 of rescore pixel

    bf16x8 afrag[2];
    #pragma unroll
    for (int ks = 0; ks < 2; ++ks)
        #pragma unroll
        for (int j = 0; j < 8; ++j)
            ((unsigned short*)&afrag[ks])[j] = f2bf(xv[ks * 8 + j]);

    const bf16x8* gBf = (const bf16x8*)cbB;

    // ---- pass 1: MFMA scan, packed running top-2 per (lane,r) slot ----
    unsigned run1[4] = {0xFFFFFFFFu, 0xFFFFFFFFu, 0xFFFFFFFFu, 0xFFFFFFFFu};
    unsigned run2[4] = {0xFFFFFFFFu, 0xFFFFFFFFu, 0xFFFFFFFFu, 0xFFFFFFFFu};
    #pragma unroll 4
    for (int nt = 0; nt < 32; ++nt) {
        bf16x8 b0 = gBf[(nt * 2 + 0) * 64 + lane];     // 1 KB coalesced, L2-hot
        bf16x8 b1 = gBf[(nt * 2 + 1) * 64 + lane];
        f32x4 c = {0.0f, 0.0f, 0.0f, 0.0f};
        c = __builtin_amdgcn_mfma_f32_16x16x32_bf16(afrag[0], b0, c, 0, 0, 0);
        c = __builtin_amdgcn_mfma_f32_16x16x32_bf16(afrag[1], b1, c, 0, 0, 0);
        const float    kn   = kn2p[nt * 16 + col];     // L1-hot
        const unsigned kidx = (unsigned)(nt * 16 + col);
        #pragma unroll
        for (int r = 0; r < 4; ++r) {
            float s = fmaf(m2r[r], c[r], kn);          // (~0.6, 5.2) -> uint-orderable
            unsigned key = (__float_as_uint(s) & 0xFFFFFE00u) | kidx;  // 9-bit k field
            unsigned mx  = max(run1[r], key);
            run1[r] = min(run1[r], key);
            run2[r] = min(run2[r], mx);                // 2nd-smallest key
        }
    }

    // ---- thresholds: cross-lane min within each 16-lane col group (uniform) ----
    float thr[4];
    #pragma unroll
    for (int r = 0; r < 4; ++r) {
        unsigned v = run1[r];
        v = min(v, (unsigned)__shfl_xor((int)v, 1));
        v = min(v, (unsigned)__shfl_xor((int)v, 2));
        v = min(v, (unsigned)__shfl_xor((int)v, 4));
        v = min(v, (unsigned)__shfl_xor((int)v, 8));
        thr[r] = __uint_as_float(v & 0xFFFFFE00u) + VQ_WINDOW;
    }

    // ---- wave flag: any slot whose 2nd-best is within threshold? (uniform) ----
    // If so, a rank>=2 in-window code exists somewhere -> slot-top1 collection
    // is insufficient; run the full recompute fallback for this wave.
    bool f = false;
    #pragma unroll
    for (int r = 0; r < 4; ++r)
        f |= (__uint_as_float(run2[r] & 0xFFFFFE00u) <= thr[r]);
    const unsigned long long waveflag = __ballot(f);   // uniform code

    if (waveflag != 0ull) {
        // ---- fallback pass 2 (R9 verbatim): bit-identical recompute ----
        #pragma unroll 4
        for (int nt = 0; nt < 32; ++nt) {
            bf16x8 b0 = gBf[(nt * 2 + 0) * 64 + lane];
            bf16x8 b1 = gBf[(nt * 2 + 1) * 64 + lane];
            f32x4 c = {0.0f, 0.0f, 0.0f, 0.0f};
            c = __builtin_amdgcn_mfma_f32_16x16x32_bf16(afrag[0], b0, c, 0, 0, 0);
            c = __builtin_amdgcn_mfma_f32_16x16x32_bf16(afrag[1], b1, c, 0, 0, 0);
            const float kn   = kn2p[nt * 16 + col];
            const int   kidx = nt * 16 + col;
            #pragma unroll
            for (int r = 0; r < 4; ++r) {
                float s = fmaf(m2r[r], c[r], kn);
                if (s <= thr[r]) {
                    int pix = wid * 16 + quad * 4 + r;     // wave-owned pixel
                    int pos = atomicAdd(&scnt[pix], 1);
                    if (pos < VQ_CAP) slist[pix][pos] = kidx;
                }
            }
        }
    } else {
        // ---- fast path: candidates are exactly the in-window slot-min1s ----
        #pragma unroll
        for (int r = 0; r < 4; ++r) {
            float s1 = __uint_as_float(run1[r] & 0xFFFFFE00u);
            if (s1 <= thr[r]) {
                int pix = wid * 16 + quad * 4 + r;         // wave-owned pixel
                int pos = atomicAdd(&scnt[pix], 1);
                if (pos < VQ_CAP) slist[pix][pos] = (int)(run1[r] & 0x1FFu);
            }
        }
    }
    __syncthreads();   // B1: candidates visible (R8/R9 safe recipe)

    // ---- exact fp32 rescore: 4 lanes/pixel, per-lane only (no shfl here) ----
    {
        const int P   = wid * 16 + (lane >> 2);    // this lane's rescore pixel
        const int sub = lane & 3;
        const int cnt = scnt[P];
        if (cnt > 1) {
            const float* xp = xblk + P;
            if (cnt <= VQ_CAP) {
                for (int i = sub; i < cnt; i += 4) {
                    const int k = slist[P][i];
                    const float* cr = cbn + (size_t)k * 64;
                    float dot = 0.0f;
                    #pragma unroll 8
                    for (int c = 0; c < 64; ++c)
                        dot = fmaf(xp[(size_t)c * 4096], cr[c], dot);  // R1 order
                    float s = fmaf(m2P, dot, kn2[k]);
                    unsigned long long key =
                        ((unsigned long long)f2ord(s) << 32) | (unsigned)k;
                    atomicMin(&spack[P], key);
                }
            } else {   // pathological overflow: exact scan of all codes
                for (int k = sub; k < 512; k += 4) {
                    const float* cr = cbn + (size_t)k * 64;
                    float dot = 0.0f;
                    #pragma unroll 8
                    for (int c = 0; c < 64; ++c)
                        dot = fmaf(xp[(size_t)c * 4096], cr[c], dot);
                    float s = fmaf(m2P, dot, kn2[k]);
                    unsigned long long key =
                        ((unsigned long long)f2ord(s) << 32) | (unsigned)k;
                    atomicMin(&spack[P], key);
                }
            }
        }
    }
    __syncthreads();   // B2: rescore results visible

    // ---- winner (packed key ties break to smallest k; cnt==1 fast path) ----
    const int cntw = scnt[wpix];
    const int bk = (cntw == 1) ? slist[wpix][0]
                               : (int)(spack[wpix] & 0xFFFFFFFFull);

    if (quad == 0) idxout[rowid * 64 + wpix] = (float)bk;

    // ---- epilogue: codes[b, :, h, wpix] = cbn[bk, :]; lane writes channels
    //      quad*16 .. quad*16+15 ----
    {
        const float4* crow = (const float4*)(cbn + (size_t)bk * 64) + quad * 4;
        float* cp = codes + ((size_t)b << 18) + (h << 6) + wpix;
        #pragma unroll
        for (int q = 0; q < 4; ++q) {
            float4 v = crow[q];
            const int c0 = quad * 16 + q * 4;
            cp[(size_t)(c0 + 0) * 4096] = v.x;
            cp[(size_t)(c0 + 1) * 4096] = v.y;
            cp[(size_t)(c0 + 2) * 4096] = v.z;
            cp[(size_t)(c0 + 3) * 4096] = v.w;
        }
    }
}

extern "C" void kernel_launch(void* const* d_in, const int* in_sizes, int n_in,
                              void* d_out, int out_size, void* d_ws, size_t ws_size,
                              hipStream_t stream) {
    const float* x  = (const float*)d_in[0];   // [32,64,64,64] fp32
    const float* cb = (const float*)d_in[1];   // [512,64] fp32

    float*          cbn  = (float*)d_ws;                       // 128 KB
    unsigned short* cbB  = (unsigned short*)(cbn + 512 * 64);  // 64 KB (frag-linear bf16)
    float*          kn2  = (float*)(cbB + 32768);              // 2 KB
    float*          kn2p = kn2 + 512;                          // 2 KB

    float* codes  = (float*)d_out;                             // 32*64*64*64 floats
    float* idxout = codes + (size_t)32 * 64 * 64 * 64;         // 131072 floats

    cb_prep_kernel<<<512, 64, 0, stream>>>(cb, cbn, cbB, kn2, kn2p);
    vq_mfma_kernel<<<2048, 256, 0, stream>>>(x, cbn, cbB, kn2, kn2p, codes, idxout);
}